// Round 2
// baseline (12114.816 us; speedup 1.0000x reference)
//
#include <hip/hip_runtime.h>

// ---------------- problem constants ----------------
constexpr int Nres = 512;
constexpr int Cs   = 384;
constexpr int Cz   = 128;
constexpr int NH   = 12;
constexpr int HC   = 16;
constexpr int NPQ  = 4;
constexpr int NPV  = 8;
constexpr int NBLK = 8;
constexpr int CATD = NH*HC + NH*NPV*3 + NH*NPV + NH*Cz; // 192+288+96+1536 = 2112
constexpr float W_L  = 0.57735026918962576f;             // sqrt(1/3)
constexpr float W_C2 = 0.11785113019775793f;             // sqrt(2/(9*PQ)) / 2

// ---------------- kernels ----------------

// init s_cur (copy of s), R = I, t = 0
__global__ void k_init(const float* __restrict__ s_in, float* __restrict__ s_cur,
                       float* __restrict__ R, float* __restrict__ t) {
    int idx = blockIdx.x * blockDim.x + threadIdx.x;
    if (idx < Nres * Cs) s_cur[idx] = s_in[idx];
    if (idx < Nres * 9) {
        int e = idx % 9;
        R[idx] = (e == 0 || e == 4 || e == 8) ? 1.f : 0.f;
    }
    if (idx < Nres * 3) t[idx] = 0.f;
}

// b_hij[h][i][j] = sum_c z[i,j,c] * w_b[c,h]   (loop-invariant: computed once)
__global__ void k_bproj(const float* __restrict__ z, const float* __restrict__ w_b,
                        float* __restrict__ b_hij) {
    int idx = blockIdx.x * blockDim.x + threadIdx.x; // i*N + j
    if (idx >= Nres * Nres) return;
    const float* zr = z + (size_t)idx * Cz;
    float acc[NH];
#pragma unroll
    for (int h = 0; h < NH; h++) acc[h] = 0.f;
    for (int c = 0; c < Cz; c++) {
        float zv = zr[c];
#pragma unroll
        for (int h = 0; h < NH; h++) acc[h] += zv * w_b[c * NH + h];
    }
#pragma unroll
    for (int h = 0; h < NH; h++) b_hij[(size_t)h * Nres * Nres + idx] = acc[h];
}

// generic: out[M x Nout] = A[M x K] @ W[K x Nout] (+bias)
// mode: 0 = store, 1 = store relu, 2 = accumulate into out
__global__ void k_matmul(const float* __restrict__ A, const float* __restrict__ W,
                         const float* __restrict__ bias, float* __restrict__ out,
                         int M, int K, int Nout, int mode) {
    int idx = blockIdx.x * blockDim.x + threadIdx.x;
    if (idx >= M * Nout) return;
    int m = idx / Nout, n = idx - m * Nout;
    const float* a = A + (size_t)m * K;
    float acc = bias ? bias[n] : 0.f;
    for (int k = 0; k < K; k++) acc += a[k] * W[(size_t)k * Nout + n];
    if (mode == 1) acc = fmaxf(acc, 0.f);
    if (mode == 2) out[idx] += acc;
    else           out[idx] = acc;
}

// q_pts in-place rigid transform: p <- R p + t.  layout (n, h, p, xyz) flat
__global__ void k_qpts(float* __restrict__ qpts, const float* __restrict__ R, const float* __restrict__ t) {
    int idx = blockIdx.x * blockDim.x + threadIdx.x;
    if (idx >= Nres * NH * NPQ) return;
    int n = idx / (NH * NPQ);
    float* p = qpts + (size_t)idx * 3;
    float y0 = p[0], y1 = p[1], y2 = p[2];
    const float* Rn = R + n * 9; const float* tn = t + n * 3;
    p[0] = Rn[0]*y0 + Rn[1]*y1 + Rn[2]*y2 + tn[0];
    p[1] = Rn[3]*y0 + Rn[4]*y1 + Rn[5]*y2 + tn[1];
    p[2] = Rn[6]*y0 + Rn[7]*y1 + Rn[8]*y2 + tn[2];
}

// kv_pts: transform raw (n, h*(PQ+PV)+p, 3) and scatter into kpts / vpts
__global__ void k_kvpts(const float* __restrict__ raw, const float* __restrict__ R, const float* __restrict__ t,
                        float* __restrict__ kpts, float* __restrict__ vpts) {
    int idx = blockIdx.x * blockDim.x + threadIdx.x;
    if (idx >= Nres * NH * (NPQ + NPV)) return;
    int n = idx / (NH * (NPQ + NPV));
    int hp = idx - n * (NH * (NPQ + NPV));
    int h = hp / (NPQ + NPV), p = hp - h * (NPQ + NPV);
    const float* s = raw + (size_t)idx * 3;
    float y0 = s[0], y1 = s[1], y2 = s[2];
    const float* Rn = R + n * 9; const float* tn = t + n * 3;
    float r0 = Rn[0]*y0 + Rn[1]*y1 + Rn[2]*y2 + tn[0];
    float r1 = Rn[3]*y0 + Rn[4]*y1 + Rn[5]*y2 + tn[1];
    float r2 = Rn[6]*y0 + Rn[7]*y1 + Rn[8]*y2 + tn[2];
    float* dst;
    if (p < NPQ) dst = kpts + ((size_t)(n * NH + h) * NPQ + p) * 3;
    else         dst = vpts + ((size_t)(n * NH + h) * NPV + (p - NPQ)) * 3;
    dst[0] = r0; dst[1] = r1; dst[2] = r2;
}

// sq_q[n,h], sq_k[n,h]
__global__ void k_sq(const float* __restrict__ qpts, const float* __restrict__ kpts,
                     float* __restrict__ sqq, float* __restrict__ sqk) {
    int idx = blockIdx.x * blockDim.x + threadIdx.x;
    if (idx >= Nres * NH) return;
    const float* q = qpts + (size_t)idx * NPQ * 3;
    const float* k = kpts + (size_t)idx * NPQ * 3;
    float a = 0.f, b = 0.f;
#pragma unroll
    for (int e = 0; e < NPQ * 3; e++) { a += q[e] * q[e]; b += k[e] * k[e]; }
    sqq[idx] = a; sqk[idx] = b;
}

// logits -> attn[h,i,j]
__global__ void k_logits(const float* __restrict__ qb, const float* __restrict__ kvb,
                         const float* __restrict__ qpts, const float* __restrict__ kpts,
                         const float* __restrict__ sqq, const float* __restrict__ sqk,
                         const float* __restrict__ b_hij, const float* __restrict__ hw,
                         float* __restrict__ attn) {
    size_t idx = (size_t)blockIdx.x * blockDim.x + threadIdx.x;
    if (idx >= (size_t)NH * Nres * Nres) return;
    int j = idx % Nres;
    size_t r = idx / Nres;
    int i = r % Nres;
    int h = r / Nres;
    const float* qv = qb + (size_t)(i * NH + h) * HC;
    const float* kv = kvb + (size_t)j * (NH * 2 * HC) + h * 2 * HC; // k part
    float sc = 0.f;
#pragma unroll
    for (int c = 0; c < HC; c++) sc += qv[c] * kv[c];
    sc *= 0.25f; // / sqrt(16)
    const float* qp = qpts + (size_t)(i * NH + h) * NPQ * 3;
    const float* kp = kpts + (size_t)(j * NH + h) * NPQ * 3;
    float cross = 0.f;
#pragma unroll
    for (int e = 0; e < NPQ * 3; e++) cross += qp[e] * kp[e];
    float d2 = sqq[i * NH + h] + sqk[j * NH + h] - 2.f * cross;
    float gamma = log1pf(expf(hw[h])); // softplus
    attn[idx] = W_L * (sc + b_hij[idx] - gamma * W_C2 * d2);
}

// softmax over j, one block (256 threads) per (h,i) row of 512
__global__ void k_softmax(float* __restrict__ attn) {
    __shared__ float red[256];
    int tid = threadIdx.x;
    float* a = attn + (size_t)blockIdx.x * Nres;
    float v0 = a[tid], v1 = a[tid + 256];
    red[tid] = fmaxf(v0, v1);
    __syncthreads();
    for (int s = 128; s > 0; s >>= 1) { if (tid < s) red[tid] = fmaxf(red[tid], red[tid + s]); __syncthreads(); }
    float mx = red[0];
    __syncthreads();
    float e0 = expf(v0 - mx), e1 = expf(v1 - mx);
    red[tid] = e0 + e1;
    __syncthreads();
    for (int s = 128; s > 0; s >>= 1) { if (tid < s) red[tid] += red[tid + s]; __syncthreads(); }
    float inv = 1.f / red[0];
    a[tid] = e0 * inv; a[tid + 256] = e1 * inv;
}

// o[i,h,c] = sum_j a[h,i,j] v[j,h,c]  -> cat[:, 0:192]
__global__ void k_o(const float* __restrict__ attn, const float* __restrict__ kvb, float* __restrict__ cat) {
    int idx = blockIdx.x * blockDim.x + threadIdx.x;
    if (idx >= Nres * NH * HC) return;
    int c = idx % HC; int r = idx / HC; int h = r % NH; int i = r / NH;
    const float* a = attn + ((size_t)h * Nres + i) * Nres;
    float acc = 0.f;
    for (int j = 0; j < Nres; j++) acc += a[j] * kvb[(size_t)j * (NH * 2 * HC) + h * 2 * HC + HC + c];
    cat[(size_t)i * CATD + h * HC + c] = acc;
}

// o_pt_global[i,h,p,x] = sum_j a[h,i,j] vpts[j,h,p,x]
__global__ void k_opt(const float* __restrict__ attn, const float* __restrict__ vpts, float* __restrict__ optg) {
    int idx = blockIdx.x * blockDim.x + threadIdx.x;
    if (idx >= Nres * NH * NPV * 3) return;
    int x = idx % 3; int r = idx / 3; int p = r % NPV; r /= NPV; int h = r % NH; int i = r / NH;
    const float* a = attn + ((size_t)h * Nres + i) * Nres;
    float acc = 0.f;
    for (int j = 0; j < Nres; j++) acc += a[j] * vpts[((size_t)(j * NH + h) * NPV + p) * 3 + x];
    optg[idx] = acc;
}

// local frame: R^T (g - t); write o_pt (cat 192..480) and norms (cat 480..576)
__global__ void k_optlocal(const float* __restrict__ optg, const float* __restrict__ R,
                           const float* __restrict__ t, float* __restrict__ cat) {
    int idx = blockIdx.x * blockDim.x + threadIdx.x; // (i, h, p)
    if (idx >= Nres * NH * NPV) return;
    int p = idx % NPV; int r = idx / NPV; int h = r % NH; int i = r / NH;
    const float* g = optg + (size_t)idx * 3;
    const float* Rn = R + i * 9; const float* tn = t + i * 3;
    float d0 = g[0] - tn[0], d1 = g[1] - tn[1], d2 = g[2] - tn[2];
    float l0 = Rn[0]*d0 + Rn[3]*d1 + Rn[6]*d2;
    float l1 = Rn[1]*d0 + Rn[4]*d1 + Rn[7]*d2;
    float l2 = Rn[2]*d0 + Rn[5]*d1 + Rn[8]*d2;
    float nrm = sqrtf(l0*l0 + l1*l1 + l2*l2 + 1e-8f);
    float* base = cat + (size_t)i * CATD;
    int hp = h * NPV + p;
    base[NH*HC + hp*3 + 0] = l0;
    base[NH*HC + hp*3 + 1] = l1;
    base[NH*HC + hp*3 + 2] = l2;
    base[NH*HC + NH*NPV*3 + hp] = nrm;
}

// o_pair[i,h,zc] = sum_j a[h,i,j] z[i,j,zc]; block per i, 128 threads (zc)
__global__ void k_opair(const float* __restrict__ attn, const float* __restrict__ z,
                        float* __restrict__ cat) {
    __shared__ float a_s[NH][128];
    int i = blockIdx.x; int tid = threadIdx.x;
    float acc[NH];
#pragma unroll
    for (int h = 0; h < NH; h++) acc[h] = 0.f;
    const float* zr = z + (size_t)i * Nres * Cz;
    for (int j0 = 0; j0 < Nres; j0 += 128) {
#pragma unroll
        for (int h = 0; h < NH; h++) a_s[h][tid] = attn[((size_t)h * Nres + i) * Nres + j0 + tid];
        __syncthreads();
        for (int jj = 0; jj < 128; jj++) {
            float zv = zr[(size_t)(j0 + jj) * Cz + tid];
#pragma unroll
            for (int h = 0; h < NH; h++) acc[h] += a_s[h][jj] * zv;
        }
        __syncthreads();
    }
    float* base = cat + (size_t)i * CATD + NH*HC + NH*NPV*3 + NH*NPV;
#pragma unroll
    for (int h = 0; h < NH; h++) base[h * Cz + tid] = acc[h];
}

// LayerNorm in place, one block (384 threads) per row
__global__ void k_ln(float* __restrict__ s, const float* __restrict__ g,
                     const float* __restrict__ b) {
    __shared__ float red[512];
    int i = blockIdx.x, tid = threadIdx.x;
    float v = s[(size_t)i * Cs + tid];
    red[tid] = v;
    if (tid < 128) red[384 + tid] = 0.f;
    __syncthreads();
    for (int st = 256; st > 0; st >>= 1) { if (tid < st) red[tid] += red[tid + st]; __syncthreads(); }
    float mean = red[0] / Cs;
    __syncthreads();
    float d = v - mean;
    red[tid] = d * d;
    if (tid < 128) red[384 + tid] = 0.f;
    __syncthreads();
    for (int st = 256; st > 0; st >>= 1) { if (tid < st) red[tid] += red[tid + st]; __syncthreads(); }
    float var = red[0] / Cs;
    s[(size_t)i * Cs + tid] = d * rsqrtf(var + 1e-5f) * g[tid] + b[tid];
}

// backbone update: upd = s@w_bb + b_bb; quat->R; compose R,t. one thread per residue
__global__ void k_bb(const float* __restrict__ s, const float* __restrict__ w_bb,
                     const float* __restrict__ b_bb, float* __restrict__ R, float* __restrict__ t) {
    int i = blockIdx.x * blockDim.x + threadIdx.x;
    if (i >= Nres) return;
    float u[6];
#pragma unroll
    for (int d = 0; d < 6; d++) u[d] = b_bb[d];
    const float* sr = s + (size_t)i * Cs;
    for (int k = 0; k < Cs; k++) {
        float sv = sr[k];
#pragma unroll
        for (int d = 0; d < 6; d++) u[d] += sv * w_bb[k * 6 + d];
    }
    float qb = u[0], qc = u[1], qd = u[2];
    float inv = rsqrtf(1.f + qb*qb + qc*qc + qd*qd);
    float w = inv, x = qb * inv, y = qc * inv, zq = qd * inv;
    float Ru[9] = {
        1.f - 2.f*(y*y + zq*zq), 2.f*(x*y - w*zq),       2.f*(x*zq + w*y),
        2.f*(x*y + w*zq),        1.f - 2.f*(x*x + zq*zq), 2.f*(y*zq - w*x),
        2.f*(x*zq - w*y),        2.f*(y*zq + w*x),        1.f - 2.f*(x*x + y*y)
    };
    float Ro[9];
#pragma unroll
    for (int e = 0; e < 9; e++) Ro[e] = R[i * 9 + e];
    float tu0 = u[3], tu1 = u[4], tu2 = u[5];
    t[i*3+0] += Ro[0]*tu0 + Ro[1]*tu1 + Ro[2]*tu2;
    t[i*3+1] += Ro[3]*tu0 + Ro[4]*tu1 + Ro[5]*tu2;
    t[i*3+2] += Ro[6]*tu0 + Ro[7]*tu1 + Ro[8]*tu2;
#pragma unroll
    for (int r = 0; r < 3; r++)
#pragma unroll
        for (int c = 0; c < 3; c++)
            R[i*9 + r*3 + c] = Ro[r*3+0]*Ru[0*3+c] + Ro[r*3+1]*Ru[1*3+c] + Ro[r*3+2]*Ru[2*3+c];
}

// final: out[i, 0:384] = s, out[i, 384:387] = t
__global__ void k_final(const float* __restrict__ s, const float* __restrict__ t,
                        float* __restrict__ out) {
    int idx = blockIdx.x * blockDim.x + threadIdx.x;
    if (idx >= Nres * (Cs + 3)) return;
    int i = idx / (Cs + 3), c = idx - i * (Cs + 3);
    float v = (c < Cs) ? s[(size_t)i * Cs + c] : t[i * 3 + (c - Cs)];
    out[idx] = v;
}

// ---------------- launch ----------------
static inline int gdiv(int n, int b) { return (n + b - 1) / b; }

extern "C" void kernel_launch(void* const* d_in, const int* in_sizes, int n_in,
                              void* d_out, int out_size, void* d_ws, size_t ws_size,
                              hipStream_t stream) {
    const float* s_in    = (const float*)d_in[0];
    const float* z       = (const float*)d_in[1];
    const float* w_q     = (const float*)d_in[2];
    const float* w_kv    = (const float*)d_in[3];
    const float* w_qpts  = (const float*)d_in[4];
    const float* w_kvpts = (const float*)d_in[5];
    const float* w_b     = (const float*)d_in[6];
    const float* hw      = (const float*)d_in[7];
    const float* w_out   = (const float*)d_in[8];
    const float* b_out   = (const float*)d_in[9];
    const float* ln1_g   = (const float*)d_in[10];
    const float* ln1_b   = (const float*)d_in[11];
    const float* w_t1    = (const float*)d_in[12];
    const float* w_t2    = (const float*)d_in[13];
    const float* w_t3    = (const float*)d_in[14];
    const float* ln2_g   = (const float*)d_in[15];
    const float* ln2_b   = (const float*)d_in[16];
    const float* w_bb    = (const float*)d_in[17];
    const float* b_bb    = (const float*)d_in[18];
    float* out = (float*)d_out;

    float* ws = (float*)d_ws;
    size_t off = 0;
    float* s_cur = ws + off; off += (size_t)Nres * Cs;            // 196608
    float* b_hij = ws + off; off += (size_t)NH * Nres * Nres;     // 3145728
    float* attn  = ws + off; off += (size_t)NH * Nres * Nres;     // 3145728
    float* qb    = ws + off; off += (size_t)Nres * NH * HC;       // 98304
    float* kvb   = ws + off; off += (size_t)Nres * NH * 2 * HC;   // 196608
    float* qpts  = ws + off; off += (size_t)Nres * NH * NPQ * 3;  // 73728
    float* kvraw = ws + off; off += (size_t)Nres * NH * (NPQ+NPV) * 3; // 221184
    float* kpts  = ws + off; off += (size_t)Nres * NH * NPQ * 3;  // 73728
    float* vpts  = ws + off; off += (size_t)Nres * NH * NPV * 3;  // 147456
    float* sqq   = ws + off; off += (size_t)Nres * NH;            // 6144
    float* sqk   = ws + off; off += (size_t)Nres * NH;            // 6144
    float* catb  = ws + off; off += (size_t)Nres * CATD;          // 1081344
    float* optg  = ws + off; off += (size_t)Nres * NH * NPV * 3;  // 147456
    float* Rbuf  = ws + off; off += (size_t)Nres * 9;             // 4608
    float* tbuf  = ws + off; off += (size_t)Nres * 3;             // 1536
    float* h1    = ws + off; off += (size_t)Nres * Cs;            // 196608
    float* h2    = ws + off; off += (size_t)Nres * Cs;            // 196608

    k_init<<<gdiv(Nres*Cs, 256), 256, 0, stream>>>(s_in, s_cur, Rbuf, tbuf);
    k_bproj<<<gdiv(Nres*Nres, 256), 256, 0, stream>>>(z, w_b, b_hij);

    for (int it = 0; it < NBLK; it++) {
        // projections
        k_matmul<<<gdiv(Nres*NH*HC, 256), 256, 0, stream>>>(s_cur, w_q, nullptr, qb, Nres, Cs, NH*HC, 0);
        k_matmul<<<gdiv(Nres*NH*2*HC, 256), 256, 0, stream>>>(s_cur, w_kv, nullptr, kvb, Nres, Cs, NH*2*HC, 0);
        k_matmul<<<gdiv(Nres*NH*NPQ*3, 256), 256, 0, stream>>>(s_cur, w_qpts, nullptr, qpts, Nres, Cs, NH*NPQ*3, 0);
        k_matmul<<<gdiv(Nres*NH*(NPQ+NPV)*3, 256), 256, 0, stream>>>(s_cur, w_kvpts, nullptr, kvraw, Nres, Cs, NH*(NPQ+NPV)*3, 0);
        // point transforms
        k_qpts<<<gdiv(Nres*NH*NPQ, 256), 256, 0, stream>>>(qpts, Rbuf, tbuf);
        k_kvpts<<<gdiv(Nres*NH*(NPQ+NPV), 256), 256, 0, stream>>>(kvraw, Rbuf, tbuf, kpts, vpts);
        k_sq<<<gdiv(Nres*NH, 256), 256, 0, stream>>>(qpts, kpts, sqq, sqk);
        // attention
        k_logits<<<gdiv(NH*Nres*Nres, 256), 256, 0, stream>>>(qb, kvb, qpts, kpts, sqq, sqk, b_hij, hw, attn);
        k_softmax<<<NH*Nres, 256, 0, stream>>>(attn);
        // outputs into cat
        k_o<<<gdiv(Nres*NH*HC, 256), 256, 0, stream>>>(attn, kvb, catb);
        k_opt<<<gdiv(Nres*NH*NPV*3, 256), 256, 0, stream>>>(attn, vpts, optg);
        k_optlocal<<<gdiv(Nres*NH*NPV, 256), 256, 0, stream>>>(optg, Rbuf, tbuf, catb);
        k_opair<<<Nres, 128, 0, stream>>>(attn, z, catb);
        // s += cat @ w_out + b_out
        k_matmul<<<gdiv(Nres*Cs, 256), 256, 0, stream>>>(catb, w_out, b_out, s_cur, Nres, CATD, Cs, 2);
        k_ln<<<Nres, Cs, 0, stream>>>(s_cur, ln1_g, ln1_b);
        // transition
        k_matmul<<<gdiv(Nres*Cs, 256), 256, 0, stream>>>(s_cur, w_t1, nullptr, h1, Nres, Cs, Cs, 1);
        k_matmul<<<gdiv(Nres*Cs, 256), 256, 0, stream>>>(h1, w_t2, nullptr, h2, Nres, Cs, Cs, 1);
        k_matmul<<<gdiv(Nres*Cs, 256), 256, 0, stream>>>(h2, w_t3, nullptr, s_cur, Nres, Cs, Cs, 2);
        k_ln<<<Nres, Cs, 0, stream>>>(s_cur, ln2_g, ln2_b);
        // backbone update
        k_bb<<<gdiv(Nres, 256), 256, 0, stream>>>(s_cur, w_bb, b_bb, Rbuf, tbuf);
    }

    k_final<<<gdiv(Nres*(Cs+3), 256), 256, 0, stream>>>(s_cur, tbuf, out);
}

// Round 3
// 2852.791 us; speedup vs baseline: 4.2467x; 4.2467x over previous
//
#include <hip/hip_runtime.h>

// ---------------- problem constants ----------------
constexpr int Nres = 512;
constexpr int Cs   = 384;
constexpr int Cz   = 128;
constexpr int NH   = 12;
constexpr int HC   = 16;
constexpr int NPQ  = 4;
constexpr int NPV  = 8;
constexpr int NBLK = 8;
constexpr int PROJD = NH*HC + NH*2*HC + NH*NPQ*3 + NH*(NPQ+NPV)*3; // 192+384+144+432 = 1152
constexpr int CATD = NH*HC + NH*NPV*3 + NH*NPV + NH*Cz;            // 2112
constexpr float W_L  = 0.57735026918962576f;  // sqrt(1/3)
constexpr float W_C2 = 0.11785113019775793f;  // sqrt(2/(9*PQ)) / 2

static inline int gdiv(int n, int b) { return (n + b - 1) / b; }

// ---------------- init ----------------
__global__ void k_init(const float* __restrict__ s_in, float* __restrict__ s_cur,
                       float* __restrict__ R, float* __restrict__ t) {
    int idx = blockIdx.x * blockDim.x + threadIdx.x;
    if (idx < Nres * Cs) s_cur[idx] = s_in[idx];
    if (idx < Nres * 9) {
        int e = idx % 9;
        R[idx] = (e == 0 || e == 4 || e == 8) ? 1.f : 0.f;
    }
    if (idx < Nres * 3) t[idx] = 0.f;
}

// concat projection weights into Wcat[384][1152]
__global__ void k_concatW(const float* __restrict__ w_q, const float* __restrict__ w_kv,
                          const float* __restrict__ w_qpts, const float* __restrict__ w_kvpts,
                          float* __restrict__ Wcat) {
    int idx = blockIdx.x * blockDim.x + threadIdx.x;
    if (idx >= Cs * PROJD) return;
    int k = idx / PROJD, n = idx - k * PROJD;
    float v;
    if      (n < 192) v = w_q[k * 192 + n];
    else if (n < 576) v = w_kv[k * 384 + (n - 192)];
    else if (n < 720) v = w_qpts[k * 144 + (n - 576)];
    else              v = w_kvpts[k * 432 + (n - 720)];
    Wcat[idx] = v;
}

// ---------------- tiled GEMM: C[M,N] = A[M,K] @ B[K,N] (+bias) ----------------
// BM=32, BN=64, BK=32; 256 threads; each thread 2x4 outputs.
// mode: 0 store, 1 relu-store, 2 accumulate (C += acc + bias)
// Requires: M%32==0, N%64==0, K%32==0 (all shapes here satisfy this)
__global__ void k_gemm(const float* __restrict__ A, const float* __restrict__ B,
                       const float* __restrict__ bias, float* __restrict__ C,
                       int M, int K, int N, int mode) {
    __shared__ float As[32][34];   // [k][m], pad 2 keeps b64 alignment + no conflicts
    __shared__ float Bs[32][64];
    const int tid = threadIdx.x;
    const int tx = tid & 15;       // N groups of 4
    const int ty = tid >> 4;       // M groups of 2
    const int m0 = blockIdx.y * 32;
    const int n0 = blockIdx.x * 64;

    float acc[2][4] = {{0.f,0.f,0.f,0.f},{0.f,0.f,0.f,0.f}};

    for (int k0 = 0; k0 < K; k0 += 32) {
#pragma unroll
        for (int l = 0; l < 4; l++) {
            int idx = tid + l * 256;
            int ak = idx & 31, am = idx >> 5;
            As[ak][am] = A[(size_t)(m0 + am) * K + k0 + ak];
        }
#pragma unroll
        for (int l = 0; l < 8; l++) {
            int idx = tid + l * 256;
            int bk = idx >> 6, bn = idx & 63;
            Bs[bk][bn] = B[(size_t)(k0 + bk) * N + n0 + bn];
        }
        __syncthreads();
#pragma unroll
        for (int kk = 0; kk < 32; kk++) {
            float a0 = As[kk][ty * 2 + 0];
            float a1 = As[kk][ty * 2 + 1];
            float4 b4 = *(const float4*)&Bs[kk][tx * 4];
            acc[0][0] += a0 * b4.x; acc[0][1] += a0 * b4.y;
            acc[0][2] += a0 * b4.z; acc[0][3] += a0 * b4.w;
            acc[1][0] += a1 * b4.x; acc[1][1] += a1 * b4.y;
            acc[1][2] += a1 * b4.z; acc[1][3] += a1 * b4.w;
        }
        __syncthreads();
    }
    const int row = m0 + ty * 2, col = n0 + tx * 4;
#pragma unroll
    for (int r = 0; r < 2; r++) {
        float* Cp = &C[(size_t)(row + r) * N + col];
#pragma unroll
        for (int c = 0; c < 4; c++) {
            float v = acc[r][c];
            if (bias) v += bias[col + c];
            if      (mode == 1) Cp[c] = fmaxf(v, 0.f);
            else if (mode == 2) Cp[c] += v;
            else                Cp[c] = v;
        }
    }
}

// ---------------- b_hij (once): b_hij[h][i][j] = sum_c z[i,j,c] w_b[c,h] ----------------
// block = 256 threads, 16 z-rows staged in LDS
__global__ void k_bproj(const float* __restrict__ z, const float* __restrict__ w_b,
                        float* __restrict__ b_hij) {
    __shared__ float zs[16][129];  // pad to kill 16-way conflicts in compute
    __shared__ float wbs[Cz * NH]; // 128*12
    const int tid = threadIdx.x;
    const int base = blockIdx.x * 16;  // global row (= i*512+j)
#pragma unroll
    for (int l = 0; l < 6; l++) {
        int idx = tid + l * 256;
        if (idx < Cz * NH) wbs[idx] = w_b[idx];
    }
#pragma unroll
    for (int l = 0; l < 8; l++) {
        int idx = tid + l * 256;
        int r = idx >> 7, c = idx & 127;
        zs[r][c] = z[(size_t)(base + r) * Cz + c];
    }
    __syncthreads();
    if (tid < 192) {
        int h = tid >> 4, r = tid & 15;
        float acc = 0.f;
        for (int c = 0; c < Cz; c++) acc += zs[r][c] * wbs[c * NH + h];
        int row = base + r;
        int i = row >> 9, j = row & 511;
        b_hij[((size_t)h * Nres + i) * Nres + j] = acc;
    }
}

// ---------------- prep: transform points, build transposed staging ----------------
// one thread per (h, i): idx -> h = idx/512, i = idx%512
__global__ void k_prep(const float* __restrict__ proj, const float* __restrict__ R,
                       const float* __restrict__ t,
                       float* __restrict__ qpts, float* __restrict__ sqq,
                       float* __restrict__ kT, float* __restrict__ kptsT,
                       float* __restrict__ sqkT, float* __restrict__ vpts) {
    int idx = blockIdx.x * blockDim.x + threadIdx.x;
    if (idx >= NH * Nres) return;
    int h = idx / Nres, i = idx % Nres;
    float R_[9], t_[3];
#pragma unroll
    for (int e = 0; e < 9; e++) R_[e] = R[i * 9 + e];
#pragma unroll
    for (int e = 0; e < 3; e++) t_[e] = t[i * 3 + e];
    const float* prow = proj + (size_t)i * PROJD;

    // q_pts
    float sq = 0.f;
#pragma unroll
    for (int p = 0; p < NPQ; p++) {
        const float* src = prow + 576 + (h * NPQ + p) * 3;
        float y0 = src[0], y1 = src[1], y2 = src[2];
        float v0 = R_[0]*y0 + R_[1]*y1 + R_[2]*y2 + t_[0];
        float v1 = R_[3]*y0 + R_[4]*y1 + R_[5]*y2 + t_[1];
        float v2 = R_[6]*y0 + R_[7]*y1 + R_[8]*y2 + t_[2];
        float* dst = qpts + (size_t)i * (NH*NPQ*3) + h * NPQ*3 + p * 3;
        dst[0] = v0; dst[1] = v1; dst[2] = v2;
        sq += v0*v0 + v1*v1 + v2*v2;
    }
    sqq[i * NH + h] = sq;

    // kv_pts
    float sk = 0.f;
#pragma unroll
    for (int p = 0; p < NPQ + NPV; p++) {
        const float* src = prow + 720 + (h * (NPQ+NPV) + p) * 3;
        float y0 = src[0], y1 = src[1], y2 = src[2];
        float v0 = R_[0]*y0 + R_[1]*y1 + R_[2]*y2 + t_[0];
        float v1 = R_[3]*y0 + R_[4]*y1 + R_[5]*y2 + t_[1];
        float v2 = R_[6]*y0 + R_[7]*y1 + R_[8]*y2 + t_[2];
        if (p < NPQ) {
            kptsT[((size_t)h * (NPQ*3) + p*3 + 0) * Nres + i] = v0;
            kptsT[((size_t)h * (NPQ*3) + p*3 + 1) * Nres + i] = v1;
            kptsT[((size_t)h * (NPQ*3) + p*3 + 2) * Nres + i] = v2;
            sk += v0*v0 + v1*v1 + v2*v2;
        } else {
            float* dst = vpts + (size_t)i * (NH*NPV*3) + h * NPV*3 + (p - NPQ) * 3;
            dst[0] = v0; dst[1] = v1; dst[2] = v2;
        }
    }
    sqkT[h * Nres + i] = sk;

    // kT[h][c][i]
#pragma unroll
    for (int c = 0; c < HC; c++)
        kT[((size_t)h * HC + c) * Nres + i] = prow[192 + h * 2 * HC + c];
}

// ---------------- fused attention: logits + softmax + o/o_pt/o_pair -> cat row ----------------
// one block per residue i, 256 threads
__global__ void __launch_bounds__(256)
k_attn(const float* __restrict__ proj, const float* __restrict__ qpts,
       const float* __restrict__ sqq, const float* __restrict__ kT,
       const float* __restrict__ kptsT, const float* __restrict__ sqkT,
       const float* __restrict__ b_hij, const float* __restrict__ hw,
       const float* __restrict__ z, const float* __restrict__ vpts,
       const float* __restrict__ R, const float* __restrict__ t,
       float* __restrict__ cat) {
    __shared__ float a_s[NH][Nres];      // 24 KB: logits -> probs
    __shared__ float qs[NH][HC];
    __shared__ float qp[NH][NPQ*3];
    __shared__ float sqq_s[NH];
    __shared__ float gam[NH];
    __shared__ float optg_s[NH*NPV*3];   // 288
    __shared__ float opair_red[NH][Cz];  // 6 KB

    const int i = blockIdx.x;
    const int tid = threadIdx.x;
    const float* prow = proj + (size_t)i * PROJD;

    if (tid < NH * HC) qs[tid >> 4][tid & 15] = prow[(tid >> 4) * HC + (tid & 15)];
    if (tid < NH * NPQ * 3) qp[tid / 12][tid % 12] = qpts[(size_t)i * 144 + tid];
    if (tid < NH) {
        sqq_s[tid] = sqq[i * NH + tid];
        gam[tid] = log1pf(__expf(hw[tid]));
    }
    __syncthreads();

    // ---- logits ----
#pragma unroll
    for (int l = 0; l < 24; l++) {
        int idx = tid + l * 256;
        int h = idx >> 9, j = idx & 511;
        float sc = 0.f;
#pragma unroll
        for (int c = 0; c < HC; c++) sc += qs[h][c] * kT[((size_t)h * HC + c) * Nres + j];
        sc *= 0.25f;
        float cr = 0.f;
#pragma unroll
        for (int e = 0; e < 12; e++) cr += qp[h][e] * kptsT[((size_t)h * 12 + e) * Nres + j];
        float d2 = sqq_s[h] + sqkT[h * Nres + j] - 2.f * cr;
        a_s[h][j] = W_L * (sc + b_hij[((size_t)h * Nres + i) * Nres + j] - gam[h] * W_C2 * d2);
    }
    __syncthreads();

    // ---- softmax: wave w handles rows 3w..3w+2 ----
    {
        int wv = tid >> 6, ln = tid & 63;
        for (int r = wv * 3; r < wv * 3 + 3; r++) {
            float vals[8];
            float m = -1e30f;
#pragma unroll
            for (int jj = 0; jj < 8; jj++) { vals[jj] = a_s[r][ln + jj * 64]; m = fmaxf(m, vals[jj]); }
#pragma unroll
            for (int off = 32; off > 0; off >>= 1) m = fmaxf(m, __shfl_xor(m, off));
            float sm = 0.f;
#pragma unroll
            for (int jj = 0; jj < 8; jj++) { vals[jj] = __expf(vals[jj] - m); sm += vals[jj]; }
#pragma unroll
            for (int off = 32; off > 0; off >>= 1) sm += __shfl_xor(sm, off);
            float inv = 1.f / sm;
#pragma unroll
            for (int jj = 0; jj < 8; jj++) a_s[r][ln + jj * 64] = vals[jj] * inv;
        }
    }
    __syncthreads();

    float* crow = cat + (size_t)i * CATD;

    // ---- o = sum_j a[h][j] * v[j,h,c] ----
    if (tid < NH * HC) {
        int h = tid >> 4, c = tid & 15;
        float acc = 0.f;
        for (int j = 0; j < Nres; j++)
            acc += a_s[h][j] * proj[(size_t)j * PROJD + 192 + HC + h * 2 * HC + c];
        crow[h * HC + c] = acc;
    }

    // ---- o_pt (global frame) ----
#pragma unroll
    for (int r = 0; r < 2; r++) {
        int idx = tid + r * 256;
        if (idx < NH * NPV * 3) {
            int h = idx / 24;
            float acc = 0.f;
            for (int j = 0; j < Nres; j++)
                acc += a_s[h][j] * vpts[(size_t)j * (NH*NPV*3) + idx];
            optg_s[idx] = acc;
        }
    }

    // ---- o_pair accumulation ----
    {
        int zc = tid & 127, half = tid >> 7;
        float accp[NH];
#pragma unroll
        for (int h = 0; h < NH; h++) accp[h] = 0.f;
        int jbeg = half * 256;
        for (int j = jbeg; j < jbeg + 256; j++) {
            float zv = z[((size_t)i * Nres + j) * Cz + zc];
#pragma unroll
            for (int h = 0; h < NH; h++) accp[h] += a_s[h][j] * zv;
        }
        if (half == 1) {
#pragma unroll
            for (int h = 0; h < NH; h++) opair_red[h][zc] = accp[h];
        }
        __syncthreads();   // optg_s + opair_red ready

        // ---- o_pt local transform + norms ----
        if (tid < NH * NPV) {
            int h = tid >> 3, p = tid & 7;
            float g0 = optg_s[h*24 + p*3 + 0], g1 = optg_s[h*24 + p*3 + 1], g2 = optg_s[h*24 + p*3 + 2];
            float d0 = g0 - t[i*3+0], d1 = g1 - t[i*3+1], d2v = g2 - t[i*3+2];
            const float* Rn = R + i * 9;
            float l0 = Rn[0]*d0 + Rn[3]*d1 + Rn[6]*d2v;
            float l1 = Rn[1]*d0 + Rn[4]*d1 + Rn[7]*d2v;
            float l2 = Rn[2]*d0 + Rn[5]*d1 + Rn[8]*d2v;
            int hp = h * NPV + p;
            crow[192 + hp*3 + 0] = l0;
            crow[192 + hp*3 + 1] = l1;
            crow[192 + hp*3 + 2] = l2;
            crow[480 + hp] = sqrtf(l0*l0 + l1*l1 + l2*l2 + 1e-8f);
        }
        if (half == 0) {
#pragma unroll
            for (int h = 0; h < NH; h++)
                crow[576 + h * Cz + zc] = accp[h] + opair_red[h][zc];
        }
    }
}

// ---------------- LayerNorm in place, one block (384 threads) per row ----------------
__global__ void k_ln(float* __restrict__ s, const float* __restrict__ g,
                     const float* __restrict__ b) {
    __shared__ float red[512];
    int i = blockIdx.x, tid = threadIdx.x;
    float v = s[(size_t)i * Cs + tid];
    red[tid] = v;
    if (tid < 128) red[384 + tid] = 0.f;
    __syncthreads();
    for (int st = 256; st > 0; st >>= 1) { if (tid < st) red[tid] += red[tid + st]; __syncthreads(); }
    float mean = red[0] / Cs;
    __syncthreads();
    float d = v - mean;
    red[tid] = d * d;
    if (tid < 128) red[384 + tid] = 0.f;
    __syncthreads();
    for (int st = 256; st > 0; st >>= 1) { if (tid < st) red[tid] += red[tid + st]; __syncthreads(); }
    float var = red[0] / Cs;
    s[(size_t)i * Cs + tid] = d * rsqrtf(var + 1e-5f) * g[tid] + b[tid];
}

// ---------------- backbone update ----------------
__global__ void k_bb(const float* __restrict__ s, const float* __restrict__ w_bb,
                     const float* __restrict__ b_bb, float* __restrict__ R, float* __restrict__ t) {
    int i = blockIdx.x * blockDim.x + threadIdx.x;
    if (i >= Nres) return;
    float u[6];
#pragma unroll
    for (int d = 0; d < 6; d++) u[d] = b_bb[d];
    const float* sr = s + (size_t)i * Cs;
    for (int k = 0; k < Cs; k++) {
        float sv = sr[k];
#pragma unroll
        for (int d = 0; d < 6; d++) u[d] += sv * w_bb[k * 6 + d];
    }
    float qb = u[0], qc = u[1], qd = u[2];
    float inv = rsqrtf(1.f + qb*qb + qc*qc + qd*qd);
    float w = inv, x = qb * inv, y = qc * inv, zq = qd * inv;
    float Ru[9] = {
        1.f - 2.f*(y*y + zq*zq), 2.f*(x*y - w*zq),       2.f*(x*zq + w*y),
        2.f*(x*y + w*zq),        1.f - 2.f*(x*x + zq*zq), 2.f*(y*zq - w*x),
        2.f*(x*zq - w*y),        2.f*(y*zq + w*x),        1.f - 2.f*(x*x + y*y)
    };
    float Ro[9];
#pragma unroll
    for (int e = 0; e < 9; e++) Ro[e] = R[i * 9 + e];
    float tu0 = u[3], tu1 = u[4], tu2 = u[5];
    t[i*3+0] += Ro[0]*tu0 + Ro[1]*tu1 + Ro[2]*tu2;
    t[i*3+1] += Ro[3]*tu0 + Ro[4]*tu1 + Ro[5]*tu2;
    t[i*3+2] += Ro[6]*tu0 + Ro[7]*tu1 + Ro[8]*tu2;
#pragma unroll
    for (int r = 0; r < 3; r++)
#pragma unroll
        for (int c = 0; c < 3; c++)
            R[i*9 + r*3 + c] = Ro[r*3+0]*Ru[0*3+c] + Ro[r*3+1]*Ru[1*3+c] + Ro[r*3+2]*Ru[2*3+c];
}

// ---------------- final pack ----------------
__global__ void k_final(const float* __restrict__ s, const float* __restrict__ t,
                        float* __restrict__ out) {
    int idx = blockIdx.x * blockDim.x + threadIdx.x;
    if (idx >= Nres * (Cs + 3)) return;
    int i = idx / (Cs + 3), c = idx - i * (Cs + 3);
    out[idx] = (c < Cs) ? s[(size_t)i * Cs + c] : t[i * 3 + (c - Cs)];
}

// ---------------- launch ----------------
extern "C" void kernel_launch(void* const* d_in, const int* in_sizes, int n_in,
                              void* d_out, int out_size, void* d_ws, size_t ws_size,
                              hipStream_t stream) {
    const float* s_in    = (const float*)d_in[0];
    const float* z       = (const float*)d_in[1];
    const float* w_q     = (const float*)d_in[2];
    const float* w_kv    = (const float*)d_in[3];
    const float* w_qpts  = (const float*)d_in[4];
    const float* w_kvpts = (const float*)d_in[5];
    const float* w_b     = (const float*)d_in[6];
    const float* hw      = (const float*)d_in[7];
    const float* w_out   = (const float*)d_in[8];
    const float* b_out   = (const float*)d_in[9];
    const float* ln1_g   = (const float*)d_in[10];
    const float* ln1_b   = (const float*)d_in[11];
    const float* w_t1    = (const float*)d_in[12];
    const float* w_t2    = (const float*)d_in[13];
    const float* w_t3    = (const float*)d_in[14];
    const float* ln2_g   = (const float*)d_in[15];
    const float* ln2_b   = (const float*)d_in[16];
    const float* w_bb    = (const float*)d_in[17];
    const float* b_bb    = (const float*)d_in[18];
    float* out = (float*)d_out;

    float* ws = (float*)d_ws;
    size_t off = 0;
    float* s_cur = ws + off; off += (size_t)Nres * Cs;             // 196608
    float* b_hij = ws + off; off += (size_t)NH * Nres * Nres;      // 3145728
    float* proj  = ws + off; off += (size_t)Nres * PROJD;          // 589824
    float* Wcat  = ws + off; off += (size_t)Cs * PROJD;            // 442368
    float* qpts  = ws + off; off += (size_t)Nres * NH * NPQ * 3;   // 73728
    float* sqq   = ws + off; off += (size_t)Nres * NH;             // 6144
    float* kT    = ws + off; off += (size_t)NH * HC * Nres;        // 98304
    float* kptsT = ws + off; off += (size_t)NH * NPQ * 3 * Nres;   // 73728
    float* sqkT  = ws + off; off += (size_t)NH * Nres;             // 6144
    float* vpts  = ws + off; off += (size_t)Nres * NH * NPV * 3;   // 147456
    float* catb  = ws + off; off += (size_t)Nres * CATD;           // 1081344
    float* Rbuf  = ws + off; off += (size_t)Nres * 9;              // 4608
    float* tbuf  = ws + off; off += (size_t)Nres * 3;              // 1536
    float* h1    = ws + off; off += (size_t)Nres * Cs;             // 196608
    float* h2    = ws + off; off += (size_t)Nres * Cs;             // 196608
    // total ~6.26M floats = 25 MB

    k_init<<<gdiv(Nres*Cs, 256), 256, 0, stream>>>(s_in, s_cur, Rbuf, tbuf);
    k_concatW<<<gdiv(Cs*PROJD, 256), 256, 0, stream>>>(w_q, w_kv, w_qpts, w_kvpts, Wcat);
    k_bproj<<<Nres*Nres/16, 256, 0, stream>>>(z, w_b, b_hij);

    for (int it = 0; it < NBLK; it++) {
        // fused projections: proj = s_cur @ Wcat  (512 x 384 x 1152)
        k_gemm<<<dim3(PROJD/64, Nres/32), 256, 0, stream>>>(s_cur, Wcat, nullptr, proj, Nres, Cs, PROJD, 0);
        // point transforms + transposed staging
        k_prep<<<gdiv(NH*Nres, 256), 256, 0, stream>>>(proj, Rbuf, tbuf, qpts, sqq, kT, kptsT, sqkT, vpts);
        // fused attention -> cat
        k_attn<<<Nres, 256, 0, stream>>>(proj, qpts, sqq, kT, kptsT, sqkT, b_hij, hw, z, vpts, Rbuf, tbuf, catb);
        // s += cat @ w_out + b_out   (512 x 2112 x 384)
        k_gemm<<<dim3(Cs/64, Nres/32), 256, 0, stream>>>(catb, w_out, b_out, s_cur, Nres, CATD, Cs, 2);
        k_ln<<<Nres, Cs, 0, stream>>>(s_cur, ln1_g, ln1_b);
        // transition
        k_gemm<<<dim3(Cs/64, Nres/32), 256, 0, stream>>>(s_cur, w_t1, nullptr, h1, Nres, Cs, Cs, 1);
        k_gemm<<<dim3(Cs/64, Nres/32), 256, 0, stream>>>(h1, w_t2, nullptr, h2, Nres, Cs, Cs, 1);
        k_gemm<<<dim3(Cs/64, Nres/32), 256, 0, stream>>>(h2, w_t3, nullptr, s_cur, Nres, Cs, Cs, 2);
        k_ln<<<Nres, Cs, 0, stream>>>(s_cur, ln2_g, ln2_b);
        // backbone update
        k_bb<<<gdiv(Nres, 256), 256, 0, stream>>>(s_cur, w_bb, b_bb, Rbuf, tbuf);
    }

    k_final<<<gdiv(Nres*(Cs+3), 256), 256, 0, stream>>>(s_cur, tbuf, out);
}

// Round 4
// 1799.245 us; speedup vs baseline: 6.7333x; 1.5855x over previous
//
#include <hip/hip_runtime.h>

// ---------------- problem constants ----------------
constexpr int Nres = 512;
constexpr int Cs   = 384;
constexpr int Cz   = 128;
constexpr int NH   = 12;
constexpr int HC   = 16;
constexpr int NPQ  = 4;
constexpr int NPV  = 8;
constexpr int NBLK = 8;
constexpr int PROJD = NH*HC + NH*2*HC + NH*NPQ*3 + NH*(NPQ+NPV)*3; // 1152
constexpr int CATD = NH*HC + NH*NPV*3 + NH*NPV + NH*Cz;            // 2112
constexpr float W_L  = 0.57735026918962576f;  // sqrt(1/3)
constexpr float W_C2 = 0.11785113019775793f;  // sqrt(2/(9*PQ)) / 2

static inline int gdiv(int n, int b) { return (n + b - 1) / b; }

// ---------------- init ----------------
__global__ void k_init(const float* __restrict__ s_in, float* __restrict__ s_cur,
                       float* __restrict__ R, float* __restrict__ t) {
    int idx = blockIdx.x * blockDim.x + threadIdx.x;
    if (idx < Nres * Cs) s_cur[idx] = s_in[idx];
    if (idx < Nres * 9) {
        int e = idx % 9;
        R[idx] = (e == 0 || e == 4 || e == 8) ? 1.f : 0.f;
    }
    if (idx < Nres * 3) t[idx] = 0.f;
}

// concat projection weights into Wcat[384][1152]
__global__ void k_concatW(const float* __restrict__ w_q, const float* __restrict__ w_kv,
                          const float* __restrict__ w_qpts, const float* __restrict__ w_kvpts,
                          float* __restrict__ Wcat) {
    int idx = blockIdx.x * blockDim.x + threadIdx.x;
    if (idx >= Cs * PROJD) return;
    int k = idx / PROJD, n = idx - k * PROJD;
    float v;
    if      (n < 192) v = w_q[k * 192 + n];
    else if (n < 576) v = w_kv[k * 384 + (n - 192)];
    else if (n < 720) v = w_qpts[k * 144 + (n - 576)];
    else              v = w_kvpts[k * 432 + (n - 720)];
    Wcat[idx] = v;
}

// ---------------- split-K tiled GEMM ----------------
// BM=64, BN=64, BK=32; 256 threads; 4x4 per thread.
// grid (N/64, M/64, nsplit); block z handles K range [z*Kc, (z+1)*Kc)
// Partials written to P[z][M][N]. Requires M%64==0, N%64==0, Kc%32==0.
__global__ void __launch_bounds__(256)
k_gemm_sk(const float* __restrict__ A, const float* __restrict__ B,
          float* __restrict__ P, int M, int K, int N, int Kc) {
    __shared__ float As[32][66];   // [k][m], pad 2: conflict-free, 8B-aligned float2 reads
    __shared__ float Bs[32][64];
    const int tid = threadIdx.x;
    const int tx = tid & 15;       // col group (4 cols)
    const int ty = tid >> 4;       // row group (4 rows)
    const int m0 = blockIdx.y * 64;
    const int n0 = blockIdx.x * 64;
    const int kbeg = blockIdx.z * Kc;

    float acc[4][4] = {};

    for (int k0 = kbeg; k0 < kbeg + Kc; k0 += 32) {
#pragma unroll
        for (int l = 0; l < 8; l++) {
            int idx = tid + l * 256;
            int ak = idx & 31, am = idx >> 5;
            As[ak][am] = A[(size_t)(m0 + am) * K + k0 + ak];
        }
#pragma unroll
        for (int l = 0; l < 8; l++) {
            int idx = tid + l * 256;
            int bk = idx >> 6, bn = idx & 63;
            Bs[bk][bn] = B[(size_t)(k0 + bk) * N + n0 + bn];
        }
        __syncthreads();
#pragma unroll
        for (int kk = 0; kk < 32; kk++) {
            float2 a01 = *(const float2*)&As[kk][ty * 4];
            float2 a23 = *(const float2*)&As[kk][ty * 4 + 2];
            float4 b4  = *(const float4*)&Bs[kk][tx * 4];
            acc[0][0] += a01.x * b4.x; acc[0][1] += a01.x * b4.y;
            acc[0][2] += a01.x * b4.z; acc[0][3] += a01.x * b4.w;
            acc[1][0] += a01.y * b4.x; acc[1][1] += a01.y * b4.y;
            acc[1][2] += a01.y * b4.z; acc[1][3] += a01.y * b4.w;
            acc[2][0] += a23.x * b4.x; acc[2][1] += a23.x * b4.y;
            acc[2][2] += a23.x * b4.z; acc[2][3] += a23.x * b4.w;
            acc[3][0] += a23.y * b4.x; acc[3][1] += a23.y * b4.y;
            acc[3][2] += a23.y * b4.z; acc[3][3] += a23.y * b4.w;
        }
        __syncthreads();
    }
    float* Pp = P + (size_t)blockIdx.z * M * N;
#pragma unroll
    for (int r = 0; r < 4; r++) {
        float4 v = make_float4(acc[r][0], acc[r][1], acc[r][2], acc[r][3]);
        *(float4*)&Pp[(size_t)(m0 + ty * 4 + r) * N + n0 + tx * 4] = v;
    }
}

// reduce partials: mode 0 store, 1 relu-store, 2 accumulate into out
__global__ void k_reduce(const float* __restrict__ P, const float* __restrict__ bias,
                         float* __restrict__ out, int MN, int N, int nsplit, int mode) {
    int idx = blockIdx.x * blockDim.x + threadIdx.x;
    if (idx >= MN) return;
    float v = 0.f;
    for (int s = 0; s < nsplit; s++) v += P[(size_t)s * MN + idx];
    if (bias) v += bias[idx % N];
    if (mode == 1) v = fmaxf(v, 0.f);
    if (mode == 2) out[idx] += v;
    else           out[idx] = v;
}

// ---------------- b_hij (once): b_hij[h][i][j] = sum_c z[i,j,c] w_b[c,h] ----------------
__global__ void k_bproj(const float* __restrict__ z, const float* __restrict__ w_b,
                        float* __restrict__ b_hij) {
    __shared__ float zs[16][129];
    __shared__ float wbs[Cz * NH];
    const int tid = threadIdx.x;
    const int base = blockIdx.x * 16;
#pragma unroll
    for (int l = 0; l < 6; l++) {
        int idx = tid + l * 256;
        if (idx < Cz * NH) wbs[idx] = w_b[idx];
    }
#pragma unroll
    for (int l = 0; l < 8; l++) {
        int idx = tid + l * 256;
        int r = idx >> 7, c = idx & 127;
        zs[r][c] = z[(size_t)(base + r) * Cz + c];
    }
    __syncthreads();
    if (tid < 192) {
        int h = tid >> 4, r = tid & 15;
        float acc = 0.f;
        for (int c = 0; c < Cz; c++) acc += zs[r][c] * wbs[c * NH + h];
        int row = base + r;
        int i = row >> 9, j = row & 511;
        b_hij[((size_t)h * Nres + i) * Nres + j] = acc;
    }
}

// ---------------- prep: transform points, build transposed staging ----------------
__global__ void k_prep(const float* __restrict__ proj, const float* __restrict__ R,
                       const float* __restrict__ t,
                       float* __restrict__ qpts, float* __restrict__ sqq,
                       float* __restrict__ kT, float* __restrict__ kptsT,
                       float* __restrict__ sqkT, float* __restrict__ vpts) {
    int idx = blockIdx.x * blockDim.x + threadIdx.x;
    if (idx >= NH * Nres) return;
    int h = idx / Nres, i = idx % Nres;
    float R_[9], t_[3];
#pragma unroll
    for (int e = 0; e < 9; e++) R_[e] = R[i * 9 + e];
#pragma unroll
    for (int e = 0; e < 3; e++) t_[e] = t[i * 3 + e];
    const float* prow = proj + (size_t)i * PROJD;

    float sq = 0.f;
#pragma unroll
    for (int p = 0; p < NPQ; p++) {
        const float* src = prow + 576 + (h * NPQ + p) * 3;
        float y0 = src[0], y1 = src[1], y2 = src[2];
        float v0 = R_[0]*y0 + R_[1]*y1 + R_[2]*y2 + t_[0];
        float v1 = R_[3]*y0 + R_[4]*y1 + R_[5]*y2 + t_[1];
        float v2 = R_[6]*y0 + R_[7]*y1 + R_[8]*y2 + t_[2];
        float* dst = qpts + (size_t)i * (NH*NPQ*3) + h * NPQ*3 + p * 3;
        dst[0] = v0; dst[1] = v1; dst[2] = v2;
        sq += v0*v0 + v1*v1 + v2*v2;
    }
    sqq[i * NH + h] = sq;

    float sk = 0.f;
#pragma unroll
    for (int p = 0; p < NPQ + NPV; p++) {
        const float* src = prow + 720 + (h * (NPQ+NPV) + p) * 3;
        float y0 = src[0], y1 = src[1], y2 = src[2];
        float v0 = R_[0]*y0 + R_[1]*y1 + R_[2]*y2 + t_[0];
        float v1 = R_[3]*y0 + R_[4]*y1 + R_[5]*y2 + t_[1];
        float v2 = R_[6]*y0 + R_[7]*y1 + R_[8]*y2 + t_[2];
        if (p < NPQ) {
            kptsT[((size_t)h * (NPQ*3) + p*3 + 0) * Nres + i] = v0;
            kptsT[((size_t)h * (NPQ*3) + p*3 + 1) * Nres + i] = v1;
            kptsT[((size_t)h * (NPQ*3) + p*3 + 2) * Nres + i] = v2;
            sk += v0*v0 + v1*v1 + v2*v2;
        } else {
            float* dst = vpts + (size_t)i * (NH*NPV*3) + h * NPV*3 + (p - NPQ) * 3;
            dst[0] = v0; dst[1] = v1; dst[2] = v2;
        }
    }
    sqkT[h * Nres + i] = sk;

#pragma unroll
    for (int c = 0; c < HC; c++)
        kT[((size_t)h * HC + c) * Nres + i] = prow[192 + h * 2 * HC + c];
}

// ---------------- fused attention ----------------
__global__ void __launch_bounds__(256)
k_attn(const float* __restrict__ proj, const float* __restrict__ qpts,
       const float* __restrict__ sqq, const float* __restrict__ kT,
       const float* __restrict__ kptsT, const float* __restrict__ sqkT,
       const float* __restrict__ b_hij, const float* __restrict__ hw,
       const float* __restrict__ z, const float* __restrict__ vpts,
       const float* __restrict__ R, const float* __restrict__ t,
       float* __restrict__ cat) {
    __shared__ float a_s[NH][Nres];
    __shared__ float qs[NH][HC];
    __shared__ float qp[NH][NPQ*3];
    __shared__ float sqq_s[NH];
    __shared__ float gam[NH];
    __shared__ float optg_s[NH*NPV*3];
    __shared__ float opair_red[NH][Cz];

    const int i = blockIdx.x;
    const int tid = threadIdx.x;
    const float* prow = proj + (size_t)i * PROJD;

    if (tid < NH * HC) qs[tid >> 4][tid & 15] = prow[(tid >> 4) * HC + (tid & 15)];
    if (tid < NH * NPQ * 3) qp[tid / 12][tid % 12] = qpts[(size_t)i * 144 + tid];
    if (tid < NH) {
        sqq_s[tid] = sqq[i * NH + tid];
        gam[tid] = log1pf(__expf(hw[tid]));
    }
    __syncthreads();

#pragma unroll
    for (int l = 0; l < 24; l++) {
        int idx = tid + l * 256;
        int h = idx >> 9, j = idx & 511;
        float sc = 0.f;
#pragma unroll
        for (int c = 0; c < HC; c++) sc += qs[h][c] * kT[((size_t)h * HC + c) * Nres + j];
        sc *= 0.25f;
        float cr = 0.f;
#pragma unroll
        for (int e = 0; e < 12; e++) cr += qp[h][e] * kptsT[((size_t)h * 12 + e) * Nres + j];
        float d2 = sqq_s[h] + sqkT[h * Nres + j] - 2.f * cr;
        a_s[h][j] = W_L * (sc + b_hij[((size_t)h * Nres + i) * Nres + j] - gam[h] * W_C2 * d2);
    }
    __syncthreads();

    {
        int wv = tid >> 6, ln = tid & 63;
        for (int r = wv * 3; r < wv * 3 + 3; r++) {
            float vals[8];
            float m = -1e30f;
#pragma unroll
            for (int jj = 0; jj < 8; jj++) { vals[jj] = a_s[r][ln + jj * 64]; m = fmaxf(m, vals[jj]); }
#pragma unroll
            for (int off = 32; off > 0; off >>= 1) m = fmaxf(m, __shfl_xor(m, off));
            float sm = 0.f;
#pragma unroll
            for (int jj = 0; jj < 8; jj++) { vals[jj] = __expf(vals[jj] - m); sm += vals[jj]; }
#pragma unroll
            for (int off = 32; off > 0; off >>= 1) sm += __shfl_xor(sm, off);
            float inv = 1.f / sm;
#pragma unroll
            for (int jj = 0; jj < 8; jj++) a_s[r][ln + jj * 64] = vals[jj] * inv;
        }
    }
    __syncthreads();

    float* crow = cat + (size_t)i * CATD;

    if (tid < NH * HC) {
        int h = tid >> 4, c = tid & 15;
        float acc = 0.f;
        for (int j = 0; j < Nres; j++)
            acc += a_s[h][j] * proj[(size_t)j * PROJD + 192 + HC + h * 2 * HC + c];
        crow[h * HC + c] = acc;
    }

#pragma unroll
    for (int r = 0; r < 2; r++) {
        int idx = tid + r * 256;
        if (idx < NH * NPV * 3) {
            int h = idx / 24;
            float acc = 0.f;
            for (int j = 0; j < Nres; j++)
                acc += a_s[h][j] * vpts[(size_t)j * (NH*NPV*3) + idx];
            optg_s[idx] = acc;
        }
    }

    {
        int zc = tid & 127, half = tid >> 7;
        float accp[NH];
#pragma unroll
        for (int h = 0; h < NH; h++) accp[h] = 0.f;
        int jbeg = half * 256;
        for (int j = jbeg; j < jbeg + 256; j++) {
            float zv = z[((size_t)i * Nres + j) * Cz + zc];
#pragma unroll
            for (int h = 0; h < NH; h++) accp[h] += a_s[h][j] * zv;
        }
        if (half == 1) {
#pragma unroll
            for (int h = 0; h < NH; h++) opair_red[h][zc] = accp[h];
        }
        __syncthreads();

        if (tid < NH * NPV) {
            int h = tid >> 3, p = tid & 7;
            float g0 = optg_s[h*24 + p*3 + 0], g1 = optg_s[h*24 + p*3 + 1], g2 = optg_s[h*24 + p*3 + 2];
            float d0 = g0 - t[i*3+0], d1 = g1 - t[i*3+1], d2v = g2 - t[i*3+2];
            const float* Rn = R + i * 9;
            float l0 = Rn[0]*d0 + Rn[3]*d1 + Rn[6]*d2v;
            float l1 = Rn[1]*d0 + Rn[4]*d1 + Rn[7]*d2v;
            float l2 = Rn[2]*d0 + Rn[5]*d1 + Rn[8]*d2v;
            int hp = h * NPV + p;
            crow[192 + hp*3 + 0] = l0;
            crow[192 + hp*3 + 1] = l1;
            crow[192 + hp*3 + 2] = l2;
            crow[480 + hp] = sqrtf(l0*l0 + l1*l1 + l2*l2 + 1e-8f);
        }
        if (half == 0) {
#pragma unroll
            for (int h = 0; h < NH; h++)
                crow[576 + h * Cz + zc] = accp[h] + opair_red[h][zc];
        }
    }
}

// ---------------- LayerNorm ----------------
__global__ void k_ln(float* __restrict__ s, const float* __restrict__ g,
                     const float* __restrict__ b) {
    __shared__ float red[512];
    int i = blockIdx.x, tid = threadIdx.x;
    float v = s[(size_t)i * Cs + tid];
    red[tid] = v;
    if (tid < 128) red[384 + tid] = 0.f;
    __syncthreads();
    for (int st = 256; st > 0; st >>= 1) { if (tid < st) red[tid] += red[tid + st]; __syncthreads(); }
    float mean = red[0] / Cs;
    __syncthreads();
    float d = v - mean;
    red[tid] = d * d;
    if (tid < 128) red[384 + tid] = 0.f;
    __syncthreads();
    for (int st = 256; st > 0; st >>= 1) { if (tid < st) red[tid] += red[tid + st]; __syncthreads(); }
    float var = red[0] / Cs;
    s[(size_t)i * Cs + tid] = d * rsqrtf(var + 1e-5f) * g[tid] + b[tid];
}

// ---------------- backbone update: one wave per residue ----------------
__global__ void k_bb(const float* __restrict__ s, const float* __restrict__ w_bb,
                     const float* __restrict__ b_bb, float* __restrict__ R, float* __restrict__ t) {
    int wv = threadIdx.x >> 6, lane = threadIdx.x & 63;
    int i = blockIdx.x * 4 + wv;
    const float* sr = s + (size_t)i * Cs;
    float u[6] = {};
#pragma unroll
    for (int k6 = 0; k6 < 6; k6++) {
        int k = lane + k6 * 64;
        float sv = sr[k];
#pragma unroll
        for (int d = 0; d < 6; d++) u[d] += sv * w_bb[k * 6 + d];
    }
#pragma unroll
    for (int off = 32; off > 0; off >>= 1)
#pragma unroll
        for (int d = 0; d < 6; d++) u[d] += __shfl_down(u[d], off);
    if (lane == 0) {
#pragma unroll
        for (int d = 0; d < 6; d++) u[d] += b_bb[d];
        float qb = u[0], qc = u[1], qd = u[2];
        float inv = rsqrtf(1.f + qb*qb + qc*qc + qd*qd);
        float w = inv, x = qb * inv, y = qc * inv, zq = qd * inv;
        float Ru[9] = {
            1.f - 2.f*(y*y + zq*zq), 2.f*(x*y - w*zq),       2.f*(x*zq + w*y),
            2.f*(x*y + w*zq),        1.f - 2.f*(x*x + zq*zq), 2.f*(y*zq - w*x),
            2.f*(x*zq - w*y),        2.f*(y*zq + w*x),        1.f - 2.f*(x*x + y*y)
        };
        float Ro[9];
#pragma unroll
        for (int e = 0; e < 9; e++) Ro[e] = R[i * 9 + e];
        float tu0 = u[3], tu1 = u[4], tu2 = u[5];
        t[i*3+0] += Ro[0]*tu0 + Ro[1]*tu1 + Ro[2]*tu2;
        t[i*3+1] += Ro[3]*tu0 + Ro[4]*tu1 + Ro[5]*tu2;
        t[i*3+2] += Ro[6]*tu0 + Ro[7]*tu1 + Ro[8]*tu2;
#pragma unroll
        for (int r = 0; r < 3; r++)
#pragma unroll
            for (int c = 0; c < 3; c++)
                R[i*9 + r*3 + c] = Ro[r*3+0]*Ru[0*3+c] + Ro[r*3+1]*Ru[1*3+c] + Ro[r*3+2]*Ru[2*3+c];
    }
}

// ---------------- final pack ----------------
__global__ void k_final(const float* __restrict__ s, const float* __restrict__ t,
                        float* __restrict__ out) {
    int idx = blockIdx.x * blockDim.x + threadIdx.x;
    if (idx >= Nres * (Cs + 3)) return;
    int i = idx / (Cs + 3), c = idx - i * (Cs + 3);
    out[idx] = (c < Cs) ? s[(size_t)i * Cs + c] : t[i * 3 + (c - Cs)];
}

// ---------------- launch ----------------
extern "C" void kernel_launch(void* const* d_in, const int* in_sizes, int n_in,
                              void* d_out, int out_size, void* d_ws, size_t ws_size,
                              hipStream_t stream) {
    const float* s_in    = (const float*)d_in[0];
    const float* z       = (const float*)d_in[1];
    const float* w_q     = (const float*)d_in[2];
    const float* w_kv    = (const float*)d_in[3];
    const float* w_qpts  = (const float*)d_in[4];
    const float* w_kvpts = (const float*)d_in[5];
    const float* w_b     = (const float*)d_in[6];
    const float* hw      = (const float*)d_in[7];
    const float* w_out   = (const float*)d_in[8];
    const float* b_out   = (const float*)d_in[9];
    const float* ln1_g   = (const float*)d_in[10];
    const float* ln1_b   = (const float*)d_in[11];
    const float* w_t1    = (const float*)d_in[12];
    const float* w_t2    = (const float*)d_in[13];
    const float* w_t3    = (const float*)d_in[14];
    const float* ln2_g   = (const float*)d_in[15];
    const float* ln2_b   = (const float*)d_in[16];
    const float* w_bb    = (const float*)d_in[17];
    const float* b_bb    = (const float*)d_in[18];
    float* out = (float*)d_out;

    float* ws = (float*)d_ws;
    size_t off = 0;
    float* s_cur = ws + off; off += (size_t)Nres * Cs;
    float* b_hij = ws + off; off += (size_t)NH * Nres * Nres;
    float* proj  = ws + off; off += (size_t)Nres * PROJD;
    float* Wcat  = ws + off; off += (size_t)Cs * PROJD;
    float* qpts  = ws + off; off += (size_t)Nres * NH * NPQ * 3;
    float* sqq   = ws + off; off += (size_t)Nres * NH;
    float* kT    = ws + off; off += (size_t)NH * HC * Nres;
    float* kptsT = ws + off; off += (size_t)NH * NPQ * 3 * Nres;
    float* sqkT  = ws + off; off += (size_t)NH * Nres;
    float* vpts  = ws + off; off += (size_t)Nres * NH * NPV * 3;
    float* catb  = ws + off; off += (size_t)Nres * CATD;
    float* Rbuf  = ws + off; off += (size_t)Nres * 9;
    float* tbuf  = ws + off; off += (size_t)Nres * 3;
    float* h1    = ws + off; off += (size_t)Nres * Cs;
    float* h2    = ws + off; off += (size_t)Nres * Cs;
    float* Pslab = ws + off; off += (size_t)11 * Nres * Cs;  // split-K partials (max: cat split=11)
    // total ~8.4M floats = 33.7 MB

    const int MNp = Nres * PROJD;   // 589824
    const int MNs = Nres * Cs;      // 196608

    k_init<<<gdiv(Nres*Cs, 256), 256, 0, stream>>>(s_in, s_cur, Rbuf, tbuf);
    k_concatW<<<gdiv(Cs*PROJD, 256), 256, 0, stream>>>(w_q, w_kv, w_qpts, w_kvpts, Wcat);
    k_bproj<<<Nres*Nres/16, 256, 0, stream>>>(z, w_b, b_hij);

    for (int it = 0; it < NBLK; it++) {
        // fused projections: proj = s_cur @ Wcat  (512 x 384 x 1152), split-K=2
        k_gemm_sk<<<dim3(PROJD/64, Nres/64, 2), 256, 0, stream>>>(s_cur, Wcat, Pslab, Nres, Cs, PROJD, 192);
        k_reduce<<<gdiv(MNp, 256), 256, 0, stream>>>(Pslab, nullptr, proj, MNp, PROJD, 2, 0);
        // point transforms + transposed staging
        k_prep<<<gdiv(NH*Nres, 256), 256, 0, stream>>>(proj, Rbuf, tbuf, qpts, sqq, kT, kptsT, sqkT, vpts);
        // fused attention -> cat
        k_attn<<<Nres, 256, 0, stream>>>(proj, qpts, sqq, kT, kptsT, sqkT, b_hij, hw, z, vpts, Rbuf, tbuf, catb);
        // s += cat @ w_out + b_out   (512 x 2112 x 384), split-K=11
        k_gemm_sk<<<dim3(Cs/64, Nres/64, 11), 256, 0, stream>>>(catb, w_out, Pslab, Nres, CATD, Cs, 192);
        k_reduce<<<gdiv(MNs, 256), 256, 0, stream>>>(Pslab, b_out, s_cur, MNs, Cs, 11, 2);
        k_ln<<<Nres, Cs, 0, stream>>>(s_cur, ln1_g, ln1_b);
        // transition (512 x 384 x 384), split-K=6
        k_gemm_sk<<<dim3(Cs/64, Nres/64, 6), 256, 0, stream>>>(s_cur, w_t1, Pslab, Nres, Cs, Cs, 64);
        k_reduce<<<gdiv(MNs, 256), 256, 0, stream>>>(Pslab, nullptr, h1, MNs, Cs, 6, 1);
        k_gemm_sk<<<dim3(Cs/64, Nres/64, 6), 256, 0, stream>>>(h1, w_t2, Pslab, Nres, Cs, Cs, 64);
        k_reduce<<<gdiv(MNs, 256), 256, 0, stream>>>(Pslab, nullptr, h2, MNs, Cs, 6, 1);
        k_gemm_sk<<<dim3(Cs/64, Nres/64, 6), 256, 0, stream>>>(h2, w_t3, Pslab, Nres, Cs, Cs, 64);
        k_reduce<<<gdiv(MNs, 256), 256, 0, stream>>>(Pslab, nullptr, s_cur, MNs, Cs, 6, 2);
        k_ln<<<Nres, Cs, 0, stream>>>(s_cur, ln2_g, ln2_b);
        // backbone update
        k_bb<<<Nres/4, 256, 0, stream>>>(s_cur, w_bb, b_bb, Rbuf, tbuf);
    }

    k_final<<<gdiv(Nres*(Cs+3), 256), 256, 0, stream>>>(s_cur, tbuf, out);
}